// Round 8
// baseline (370.498 us; speedup 1.0000x reference)
//
#include <hip/hip_runtime.h>

typedef unsigned short u16;
typedef unsigned int u32;
typedef __attribute__((ext_vector_type(8))) short bf16x8;
typedef __attribute__((ext_vector_type(4))) float f32x4;

#define KDIM   512
#define NROWS  1024
#define NCLS   100000
#define CPAD   100096   // 782*128
#define NSTRIP 782      // 128-wide column strips
#define NMT    8        // 1024/128
#define NWG    (NSTRIP*NMT)   // 6256

#define COS_M_C   0.8775825618903728f
#define SIN_M_C   0.4794255386042030f
#define THRESH_C  (-0.8775825618903728f)
#define MM_C      0.2397127693021015f
#define S_C       64.0f

__device__ __forceinline__ u16 f2bf(float f) {
    u32 x = __float_as_uint(f);
    x += 0x7fffu + ((x >> 16) & 1u);   // RNE
    return (u16)(x >> 16);
}
__device__ __forceinline__ float bf2f(u16 u) {
    return __uint_as_float(((u32)u) << 16);
}
__device__ __forceinline__ u32 pack2(float a, float b) {
    return (u32)f2bf(a) | ((u32)f2bf(b) << 16);
}

// Image geometry: per (tile, kt) an 8 KB block = 64 LINES of 128 B.
// Line L holds rows 2L and 2L+1 (of 128); each row = 32 k bf16 = 4 chunks
// of 16 B. Chunk (r,q) lives at line r>>1, slot ((r&1)*4 + q + (r>>1)) & 7
// (bijective within the line). 128-B lines span all 32 banks; a 16-lane
// quarter (fixed q, rows wr..wr+15) hits each bank-quad exactly twice --
// the R4-measured-zero-conflict geometry. Slot is invariant under r += 16,
// so fragment m keeps the +m*512 u16 stride.
__device__ __forceinline__ int imgoff(int r, int q) {   // u16 units
    return (r >> 1) * 64 + ((((r & 1) << 2) + q + (r >> 1)) & 7) * 8;
}

__device__ __forceinline__ void gld16(const void* g, void* l) {
    __builtin_amdgcn_global_load_lds(
        (const __attribute__((address_space(1))) void*)g,
        (__attribute__((address_space(3))) void*)l, 16, 0, 0);
}

// ---------------- kernel 1: row-normalize embeddings ----------------
__global__ __launch_bounds__(64)
void norm_emb_k(const float* __restrict__ emb, float* __restrict__ Af,
                u16* __restrict__ Aw) {
    const int i = blockIdx.x, l = threadIdx.x;
    const float* e = emb + i * KDIM;
    float4 v0 = *(const float4*)(e + l * 8);
    float4 v1 = *(const float4*)(e + l * 8 + 4);
    float s = v0.x*v0.x + v0.y*v0.y + v0.z*v0.z + v0.w*v0.w
            + v1.x*v1.x + v1.y*v1.y + v1.z*v1.z + v1.w*v1.w;
    #pragma unroll
    for (int o = 1; o < 64; o <<= 1) s += __shfl_xor(s, o);
    float inv = rsqrtf(s);
    float4 n0 = make_float4(v0.x*inv, v0.y*inv, v0.z*inv, v0.w*inv);
    float4 n1 = make_float4(v1.x*inv, v1.y*inv, v1.z*inv, v1.w*inv);
    *(float4*)(Af + i*KDIM + l*8)     = n0;
    *(float4*)(Af + i*KDIM + l*8 + 4) = n1;
    // lane l owns k = l*8..l*8+7 -> kt = l>>2, chunk q = l&3
    const int mt = i >> 7, row = i & 127;
    uint4 w;
    w.x = pack2(n0.x, n0.y);
    w.y = pack2(n0.z, n0.w);
    w.z = pack2(n1.x, n1.y);
    w.w = pack2(n1.z, n1.w);
    *(uint4*)(Aw + mt*65536 + (l>>2)*4096 + imgoff(row, l & 3)) = w;
}

// ------- kernel 2: transpose+convert W [512][100000]f32 -> Bn image + norms
__global__ __launch_bounds__(128)
void transpose_norm_k(const float* __restrict__ Kg, u16* __restrict__ Bn,
                      float* __restrict__ kinv) {
    __shared__ float Ls[32 * 132];           // 32 k-rows x 128 cols, pad 132
    const int t  = threadIdx.x;
    const int jb = blockIdx.x * 128;
    const int j  = jb + t;
    u16* bstrip = Bn + (size_t)blockIdx.x * 65536;   // 16 kt * 4096 u16
    float acc = 0.f;
    for (int kc = 0; kc < 16; ++kc) {        // kc == kt (32 k each)
        #pragma unroll
        for (int it = 0; it < 8; ++it) {
            int fid  = it * 128 + t;
            int r    = fid >> 5;
            int c4   = (fid & 31) * 4;
            int gcol = jb + c4;
            float4 v;
            if (gcol + 3 < NCLS) {
                v = *(const float4*)(Kg + (kc*32 + r) * NCLS + gcol);
            } else {
                v.x = (gcol + 0 < NCLS) ? Kg[(kc*32 + r)*NCLS + gcol + 0] : 0.f;
                v.y = (gcol + 1 < NCLS) ? Kg[(kc*32 + r)*NCLS + gcol + 1] : 0.f;
                v.z = (gcol + 2 < NCLS) ? Kg[(kc*32 + r)*NCLS + gcol + 2] : 0.f;
                v.w = (gcol + 3 < NCLS) ? Kg[(kc*32 + r)*NCLS + gcol + 3] : 0.f;
            }
            *(float4*)(Ls + r * 132 + c4) = v;
        }
        __syncthreads();
        #pragma unroll
        for (int q = 0; q < 4; ++q) {        // chunk q covers k = kc*32+q*8..
            u16 u[8];
            #pragma unroll
            for (int e = 0; e < 8; ++e) {
                float v = Ls[(q*8 + e) * 132 + t];
                acc += v * v;
                u[e] = f2bf(v);
            }
            uint4 w;
            w.x = (u32)u[0] | ((u32)u[1] << 16);
            w.y = (u32)u[2] | ((u32)u[3] << 16);
            w.z = (u32)u[4] | ((u32)u[5] << 16);
            w.w = (u32)u[6] | ((u32)u[7] << 16);
            *(uint4*)(bstrip + kc*4096 + imgoff(t, q)) = w;
        }
        __syncthreads();
    }
    kinv[j] = rsqrtf(fmaxf(acc, 1e-30f));
}

// ---------------- kernel 3: per-row target logit & margins ----------------
__global__ __launch_bounds__(64)
void target_k(const float* __restrict__ Af, const u16* __restrict__ Bn,
              const float* __restrict__ kinv, const int* __restrict__ label,
              float* __restrict__ tgt, float* __restrict__ ctm,
              float* __restrict__ fin) {
    const int i = blockIdx.x, l = threadIdx.x;
    const int lab = label[i];
    float4 a0 = *(const float4*)(Af + i * KDIM + l * 8);
    float4 a1 = *(const float4*)(Af + i * KDIM + l * 8 + 4);
    uint4 bv = *(const uint4*)(Bn + (size_t)(lab >> 7) * 65536
               + (l >> 2) * 4096 + imgoff(lab & 127, l & 3));
    float d = a0.x * bf2f((u16)(bv.x & 0xffff)) + a0.y * bf2f((u16)(bv.x >> 16))
            + a0.z * bf2f((u16)(bv.y & 0xffff)) + a0.w * bf2f((u16)(bv.y >> 16))
            + a1.x * bf2f((u16)(bv.z & 0xffff)) + a1.y * bf2f((u16)(bv.z >> 16))
            + a1.z * bf2f((u16)(bv.w & 0xffff)) + a1.w * bf2f((u16)(bv.w >> 16));
    #pragma unroll
    for (int o = 1; o < 64; o <<= 1) d += __shfl_xor(d, o);
    if (l == 0) {
        float c = d * kinv[lab];
        c = fminf(fmaxf(c, -1.f), 1.f);
        tgt[i] = c;
        float sn = sqrtf(fmaxf(1.f - c*c, 0.f));
        float cm = c * COS_M_C - sn * SIN_M_C;
        ctm[i] = cm;
        fin[i] = (c > THRESH_C) ? cm : (c - MM_C);
    }
}

// ---------------- kernel 4: t_new scalar ----------------
__global__ __launch_bounds__(256)
void tnew_k(const float* __restrict__ tgt, const float* __restrict__ tin,
            float* __restrict__ tnw) {
    __shared__ float red[256];
    const int t = threadIdx.x;
    float s = tgt[t] + tgt[t + 256] + tgt[t + 512] + tgt[t + 768];
    red[t] = s;
    __syncthreads();
    for (int o = 128; o > 0; o >>= 1) {
        if (t < o) red[t] += red[t + o];
        __syncthreads();
    }
    if (t == 0) tnw[0] = red[0] * (0.01f / 1024.f) + 0.99f * tin[0];
}

// ---------------- kernel 5: 128x128 bf16 MFMA GEMM, 4 blocks/CU ----------
// BK=32, 4 waves (2x2), wave-tile 64x64, LDS 32KB double-buffered.
// Per kt: STAGE(next) -> vmcnt(4) -> barrier -> 8 ds_read_b128 -> lgkm(0)
// -> sched_barrier -> barrier(reads done) -> 16 MFMA.
__global__ __launch_bounds__(256, 4)
void gemm_k(const u16* __restrict__ A, const u16* __restrict__ B,
            const float* __restrict__ kinv, const float* __restrict__ ctm,
            const float* __restrict__ fin, const int* __restrict__ label,
            const float* __restrict__ tnwp, float* __restrict__ out) {
    __shared__ __align__(16) u16 As[2][4096];   // 2 x 8 KB
    __shared__ __align__(16) u16 Bs[2][4096];   // 2 x 8 KB
    const int tid  = threadIdx.x;
    const int wave = tid >> 6, lane = tid & 63;

    // XCD-chunked swizzle (6256 = 8*782, exact): mt fast -> B strip shared.
    const int L  = blockIdx.x;
    const int w  = (L & 7) * NSTRIP + (L >> 3);
    const int mt = w & 7;
    const int cs = w >> 3;
    const int m0 = mt * 128;
    const int j0 = cs * 128;
    const int wr = (wave >> 1) * 64;
    const int wc = (wave & 1) * 64;

    f32x4 acc[4][4] = {};

    const u16* gA = A + mt * 65536 + tid * 8;
    const u16* gB = B + (size_t)cs * 65536 + tid * 8;
    const int  ld = tid * 8;             // u16 offset (lane*16B within wave)

    const int rowA = wr + (lane & 15);
    const int colB = wc + (lane & 15);
    const int qh   = lane >> 4;          // 0..3 = k-quarter
    const int aBase = imgoff(rowA, qh);  // u16 units; +m*512 per fragment
    const int bBase = imgoff(colB, qh);

#define STAGE(b, kt) do {                                        \
    gld16(gA + (kt)*4096,        &As[b][ld]);                    \
    gld16(gA + (kt)*4096 + 2048, &As[b][ld + 2048]);             \
    gld16(gB + (kt)*4096,        &Bs[b][ld]);                    \
    gld16(gB + (kt)*4096 + 2048, &Bs[b][ld + 2048]);             \
} while (0)

    STAGE(0, 0);
    #pragma unroll 2
    for (int kt = 0; kt < 16; ++kt) {
        const int cur = kt & 1;
        if (kt < 15) {
            STAGE(cur ^ 1, kt + 1);
            asm volatile("s_waitcnt vmcnt(4)" ::: "memory");
        } else {
            asm volatile("s_waitcnt vmcnt(0)" ::: "memory");
        }
        __builtin_amdgcn_s_barrier();    // buf[cur] fully staged

        bf16x8 af[4], bfr[4];
        #pragma unroll
        for (int m = 0; m < 4; ++m)
            af[m] = *(const bf16x8*)(As[cur] + aBase + m * 512);
        #pragma unroll
        for (int n = 0; n < 4; ++n)
            bfr[n] = *(const bf16x8*)(Bs[cur] + bBase + n * 512);
        asm volatile("s_waitcnt lgkmcnt(0)" ::: "memory");
        __builtin_amdgcn_sched_barrier(0);   // rule 18: keep MFMA below wait
        __builtin_amdgcn_s_barrier();        // all waves done reading cur

        #pragma unroll
        for (int m = 0; m < 4; ++m)
            #pragma unroll
            for (int n = 0; n < 4; ++n)
                acc[m][n] = __builtin_amdgcn_mfma_f32_16x16x32_bf16(
                                af[m], bfr[n], acc[m][n], 0, 0, 0);
    }
#undef STAGE

    // fused epilogue (scattered, R4/R7-validated: WRITE_SIZE exact 400 MB)
    const float tnew = *tnwp;
    const int colbase = j0 + wc + (lane & 15);
    float kv[4];
    int cols[4];
    #pragma unroll
    for (int n = 0; n < 4; ++n) {
        cols[n] = colbase + n * 16;
        kv[n] = kinv[cols[n]];
    }
    #pragma unroll
    for (int m = 0; m < 4; ++m) {
        const int rb = m0 + wr + m * 16 + (lane >> 4) * 4;
        #pragma unroll
        for (int r = 0; r < 4; ++r) {
            const int row = rb + r;
            const int lab = label[row];
            const float ct = ctm[row];
            const float fv = fin[row];
            float* orow = out + (size_t)row * NCLS;
            #pragma unroll
            for (int n = 0; n < 4; ++n) {
                float c = acc[m][n][r] * kv[n];
                c = fminf(fmaxf(c, -1.f), 1.f);
                float v = (c > ct) ? c * (tnew + c) : c;
                v = (cols[n] == lab) ? fv : v;
                if (cols[n] < NCLS)
                    orow[cols[n]] = v * S_C;
            }
        }
    }
}

extern "C" void kernel_launch(void* const* d_in, const int* in_sizes, int n_in,
                              void* d_out, int out_size, void* d_ws, size_t ws_size,
                              hipStream_t stream) {
    const float* emb = (const float*)d_in[0];
    const float* Kg  = (const float*)d_in[1];
    const float* tin = (const float*)d_in[2];
    const int*   lab = (const int*)d_in[3];
    float* out = (float*)d_out;

    char* w = (char*)d_ws;
    u16*   Bn   = (u16*)w;                         // 782*65536*2 = 102,498,304
    u16*   Aw   = (u16*)(w + 102498304);           // 8*65536*2   =   1,048,576
    float* Af   = (float*)(w + 103546880);         // 1024*512*4  =   2,097,152
    float* kinv = (float*)(w + 105644032);         // CPAD*4      =     400,384
    float* tgt  = (float*)(w + 106044416);
    float* ctmv = (float*)(w + 106048512);
    float* finv = (float*)(w + 106052608);
    float* tnw  = (float*)(w + 106056704);

    norm_emb_k<<<NROWS, 64, 0, stream>>>(emb, Af, Aw);
    transpose_norm_k<<<NSTRIP, 128, 0, stream>>>(Kg, Bn, kinv);
    target_k<<<NROWS, 64, 0, stream>>>(Af, Bn, kinv, lab, tgt, ctmv, finv);
    tnew_k<<<1, 256, 0, stream>>>(tgt, tin, tnw);
    gemm_k<<<NWG, 256, 0, stream>>>(
        Aw, Bn, kinv, ctmv, finv, lab, tnw, out);
}

// Round 9
// 354.736 us; speedup vs baseline: 1.0444x; 1.0444x over previous
//
#include <hip/hip_runtime.h>

typedef unsigned short u16;
typedef unsigned int u32;
typedef __attribute__((ext_vector_type(8))) short bf16x8;
typedef __attribute__((ext_vector_type(4))) float f32x4;

#define KDIM   512
#define NROWS  1024
#define NCLS   100000
#define CPAD   100096   // 391*256
#define NSTRIP 391      // 256-wide column strips
#define NMT    4        // 1024/256
#define NWG    (NSTRIP*NMT)   // 1564

#define COS_M_C   0.8775825618903728f
#define SIN_M_C   0.4794255386042030f
#define THRESH_C  (-0.8775825618903728f)
#define MM_C      0.2397127693021015f
#define S_C       64.0f

__device__ __forceinline__ u16 f2bf(float f) {
    u32 x = __float_as_uint(f);
    x += 0x7fffu + ((x >> 16) & 1u);   // RNE
    return (u16)(x >> 16);
}
__device__ __forceinline__ float bf2f(u16 u) {
    return __uint_as_float(((u32)u) << 16);
}
__device__ __forceinline__ u32 pack2(float a, float b) {
    return (u32)f2bf(a) | ((u32)f2bf(b) << 16);
}

// Image geometry: per (tile, ks) a 16 KB block = 256 rows x 32 k bf16
// = 128 LINES of 128 B. Line L holds rows 2L,2L+1; row = 4 chunks of 16 B.
// Chunk (r,q) at line r>>1, slot ((r&1)*4 + q + (r>>1)) & 7.
// R8-measured: SQ_LDS_BANK_CONFLICT == 0 with this geometry.
// Slot invariant under r += 16  ->  fragment m stride = 512 u16.
__device__ __forceinline__ int imgoff(int r, int q) {   // u16 units
    return (r >> 1) * 64 + ((((r & 1) << 2) + q + (r >> 1)) & 7) * 8;
}

__device__ __forceinline__ void gld16(const void* g, void* l) {
    __builtin_amdgcn_global_load_lds(
        (const __attribute__((address_space(1))) void*)g,
        (__attribute__((address_space(3))) void*)l, 16, 0, 0);
}

// A image: [4 mt][16 ks][16KB block]  (stride per mt = 131072 u16)
// B image: [391 strip][16 ks][16KB block] (stride per strip = 131072 u16)

// ---------------- kernel 1: row-normalize embeddings ----------------
__global__ __launch_bounds__(64)
void norm_emb_k(const float* __restrict__ emb, float* __restrict__ Af,
                u16* __restrict__ Aw) {
    const int i = blockIdx.x, l = threadIdx.x;
    const float* e = emb + i * KDIM;
    float4 v0 = *(const float4*)(e + l * 8);
    float4 v1 = *(const float4*)(e + l * 8 + 4);
    float s = v0.x*v0.x + v0.y*v0.y + v0.z*v0.z + v0.w*v0.w
            + v1.x*v1.x + v1.y*v1.y + v1.z*v1.z + v1.w*v1.w;
    #pragma unroll
    for (int o = 1; o < 64; o <<= 1) s += __shfl_xor(s, o);
    float inv = rsqrtf(s);
    float4 n0 = make_float4(v0.x*inv, v0.y*inv, v0.z*inv, v0.w*inv);
    float4 n1 = make_float4(v1.x*inv, v1.y*inv, v1.z*inv, v1.w*inv);
    *(float4*)(Af + i*KDIM + l*8)     = n0;
    *(float4*)(Af + i*KDIM + l*8 + 4) = n1;
    // lane l owns k = l*8..l*8+7 -> ks = l>>2, chunk q = l&3
    const int mt = i >> 8, row = i & 255;
    uint4 w;
    w.x = pack2(n0.x, n0.y);
    w.y = pack2(n0.z, n0.w);
    w.z = pack2(n1.x, n1.y);
    w.w = pack2(n1.z, n1.w);
    *(uint4*)(Aw + mt*131072 + (l>>2)*8192 + imgoff(row, l & 3)) = w;
}

// ------- kernel 2: transpose+convert W [512][100000]f32 -> Bn image + norms
__global__ __launch_bounds__(256)
void transpose_norm_k(const float* __restrict__ Kg, u16* __restrict__ Bn,
                      float* __restrict__ kinv) {
    __shared__ float Ls[32 * 260];           // 32 k-rows x 256 cols, pad 260
    const int t  = threadIdx.x;
    const int jb = blockIdx.x * 256;
    const int j  = jb + t;
    u16* bstrip = Bn + (size_t)blockIdx.x * 131072;
    float acc = 0.f;
    for (int kc = 0; kc < 16; ++kc) {        // kc == ks (32 k each)
        #pragma unroll
        for (int it = 0; it < 8; ++it) {
            int fid  = it * 256 + t;
            int r    = fid >> 6;
            int c4   = (fid & 63) * 4;
            int gcol = jb + c4;
            float4 v;
            if (gcol + 3 < NCLS) {
                v = *(const float4*)(Kg + (kc*32 + r) * NCLS + gcol);
            } else {
                v.x = (gcol + 0 < NCLS) ? Kg[(kc*32 + r)*NCLS + gcol + 0] : 0.f;
                v.y = (gcol + 1 < NCLS) ? Kg[(kc*32 + r)*NCLS + gcol + 1] : 0.f;
                v.z = (gcol + 2 < NCLS) ? Kg[(kc*32 + r)*NCLS + gcol + 2] : 0.f;
                v.w = (gcol + 3 < NCLS) ? Kg[(kc*32 + r)*NCLS + gcol + 3] : 0.f;
            }
            *(float4*)(Ls + r * 260 + c4) = v;
        }
        __syncthreads();
        #pragma unroll
        for (int q = 0; q < 4; ++q) {        // chunk q covers k = kc*32+q*8..
            u16 u[8];
            #pragma unroll
            for (int e = 0; e < 8; ++e) {
                float v = Ls[(q*8 + e) * 260 + t];
                acc += v * v;
                u[e] = f2bf(v);
            }
            uint4 w;
            w.x = (u32)u[0] | ((u32)u[1] << 16);
            w.y = (u32)u[2] | ((u32)u[3] << 16);
            w.z = (u32)u[4] | ((u32)u[5] << 16);
            w.w = (u32)u[6] | ((u32)u[7] << 16);
            *(uint4*)(bstrip + kc*8192 + imgoff(t, q)) = w;
        }
        __syncthreads();
    }
    kinv[j] = rsqrtf(fmaxf(acc, 1e-30f));
}

// ---------------- kernel 3: per-row target logit & margins ----------------
__global__ __launch_bounds__(64)
void target_k(const float* __restrict__ Af, const u16* __restrict__ Bn,
              const float* __restrict__ kinv, const int* __restrict__ label,
              float* __restrict__ tgt, float* __restrict__ ctm,
              float* __restrict__ fin) {
    const int i = blockIdx.x, l = threadIdx.x;
    const int lab = label[i];
    float4 a0 = *(const float4*)(Af + i * KDIM + l * 8);
    float4 a1 = *(const float4*)(Af + i * KDIM + l * 8 + 4);
    uint4 bv = *(const uint4*)(Bn + (size_t)(lab >> 8) * 131072
               + (l >> 2) * 8192 + imgoff(lab & 255, l & 3));
    float d = a0.x * bf2f((u16)(bv.x & 0xffff)) + a0.y * bf2f((u16)(bv.x >> 16))
            + a0.z * bf2f((u16)(bv.y & 0xffff)) + a0.w * bf2f((u16)(bv.y >> 16))
            + a1.x * bf2f((u16)(bv.z & 0xffff)) + a1.y * bf2f((u16)(bv.z >> 16))
            + a1.z * bf2f((u16)(bv.w & 0xffff)) + a1.w * bf2f((u16)(bv.w >> 16));
    #pragma unroll
    for (int o = 1; o < 64; o <<= 1) d += __shfl_xor(d, o);
    if (l == 0) {
        float c = d * kinv[lab];
        c = fminf(fmaxf(c, -1.f), 1.f);
        tgt[i] = c;
        float sn = sqrtf(fmaxf(1.f - c*c, 0.f));
        float cm = c * COS_M_C - sn * SIN_M_C;
        ctm[i] = cm;
        fin[i] = (c > THRESH_C) ? cm : (c - MM_C);
    }
}

// ---------------- kernel 4: t_new scalar ----------------
__global__ __launch_bounds__(256)
void tnew_k(const float* __restrict__ tgt, const float* __restrict__ tin,
            float* __restrict__ tnw) {
    __shared__ float red[256];
    const int t = threadIdx.x;
    float s = tgt[t] + tgt[t + 256] + tgt[t + 512] + tgt[t + 768];
    red[t] = s;
    __syncthreads();
    for (int o = 128; o > 0; o >>= 1) {
        if (t < o) red[t] += red[t + o];
        __syncthreads();
    }
    if (t == 0) tnw[0] = red[0] * (0.01f / 1024.f) + 0.99f * tin[0];
}

// ------- kernel 5: 256x256 GEMM, counted-vmcnt 4-slot ring schedule -------
// 8 waves (2M x 4N), wave-tile 128x64. K = 16 steps of 32-k.
// LDS ring: 4 slots x (A 16KB + B 16KB). Steady state: 3 steps of loads
// (12 gld16/thread) in flight -> vmcnt(12), never 0 mid-loop.
// Per step: bar | stage s+3 | vmcnt | bar | 12 ds_read | lgkm(4) |
//           16 MFMA | lgkm(0) | 16 MFMA.
__global__ __launch_bounds__(512, 1)
void gemm_k(const u16* __restrict__ A, const u16* __restrict__ B,
            const float* __restrict__ kinv, const float* __restrict__ ctm,
            const float* __restrict__ fin, const int* __restrict__ label,
            const float* __restrict__ tnwp, float* __restrict__ out) {
    __shared__ __align__(16) u16 S[4][16384];   // 4 x 32 KB
    const int tid  = threadIdx.x;
    const int wave = tid >> 6, lane = tid & 63;

    // m204 bijective XCD swizzle: nwg=1564, q=195, r=4; mt fast.
    const int L   = blockIdx.x;
    const int xcd = L & 7;
    const int wg  = (xcd < 4 ? xcd * 196 : 784 + (xcd - 4) * 195) + (L >> 3);
    const int mt  = wg & 3;
    const int cs  = wg >> 2;
    const int m0  = mt * 256;
    const int j0  = cs * 256;
    const int wm  = wave >> 2;           // 0..1  (M half)
    const int wn  = wave & 3;            // 0..3  (N quarter)
    const int wrl = wm * 128;
    const int wcl = wn * 64;

    f32x4 acc[8][4] = {};

    const u16* gA = A + mt * 131072 + tid * 8;
    const u16* gB = B + (size_t)cs * 131072 + tid * 8;

    const int lr = lane & 15, q = lane >> 4;
    const int aB = imgoff(wrl + lr, q);          // + m*512 per fragment
    const int bB = 8192 + imgoff(wcl + lr, q);   // + n*512 per fragment

#define STAGE(s) do {                                            \
    gld16(gA + (s)*8192,        &S[(s)&3][tid*8]);               \
    gld16(gA + (s)*8192 + 4096, &S[(s)&3][tid*8 + 4096]);        \
    gld16(gB + (s)*8192,        &S[(s)&3][8192  + tid*8]);       \
    gld16(gB + (s)*8192 + 4096, &S[(s)&3][12288 + tid*8]);       \
} while (0)

    STAGE(0); STAGE(1); STAGE(2);
    #pragma unroll
    for (int s = 0; s < 16; ++s) {
        __builtin_amdgcn_s_barrier();        // all reads of step s-1 done
        if (s + 3 < 16) STAGE(s + 3);        // refill slot (s-1)&3
        if (s <= 12)      asm volatile("s_waitcnt vmcnt(12)" ::: "memory");
        else if (s == 13) asm volatile("s_waitcnt vmcnt(8)"  ::: "memory");
        else if (s == 14) asm volatile("s_waitcnt vmcnt(4)"  ::: "memory");
        else              asm volatile("s_waitcnt vmcnt(0)"  ::: "memory");
        __builtin_amdgcn_s_barrier();        // slot s landed (all waves)
        __builtin_amdgcn_sched_barrier(0);

        const u16* sa = S[s & 3];
        bf16x8 af[4], bf[4], af2[4];
        #pragma unroll
        for (int m = 0; m < 4; ++m)
            af[m]  = *(const bf16x8*)(sa + aB + m * 512);
        #pragma unroll
        for (int n = 0; n < 4; ++n)
            bf[n]  = *(const bf16x8*)(sa + bB + n * 512);
        #pragma unroll
        for (int m = 0; m < 4; ++m)
            af2[m] = *(const bf16x8*)(sa + aB + 2048 + m * 512);

        asm volatile("s_waitcnt lgkmcnt(4)" ::: "memory"); // af,bf ready
        __builtin_amdgcn_sched_barrier(0);
        __builtin_amdgcn_s_setprio(1);
        #pragma unroll
        for (int m = 0; m < 4; ++m)
            #pragma unroll
            for (int n = 0; n < 4; ++n)
                acc[m][n] = __builtin_amdgcn_mfma_f32_16x16x32_bf16(
                                af[m], bf[n], acc[m][n], 0, 0, 0);
        __builtin_amdgcn_s_setprio(0);

        asm volatile("s_waitcnt lgkmcnt(0)" ::: "memory"); // af2 ready
        __builtin_amdgcn_sched_barrier(0);
        __builtin_amdgcn_s_setprio(1);
        #pragma unroll
        for (int m = 0; m < 4; ++m)
            #pragma unroll
            for (int n = 0; n < 4; ++n)
                acc[4 + m][n] = __builtin_amdgcn_mfma_f32_16x16x32_bf16(
                                af2[m], bf[n], acc[4 + m][n], 0, 0, 0);
        __builtin_amdgcn_s_setprio(0);
    }
#undef STAGE

    // fused epilogue (scattered dword, R4/R7/R8-validated)
    const float tnew = *tnwp;
    const int colbase = j0 + wcl + (lane & 15);
    float kv[4];
    int cols[4];
    #pragma unroll
    for (int n = 0; n < 4; ++n) {
        cols[n] = colbase + n * 16;
        kv[n] = kinv[cols[n]];
    }
    #pragma unroll
    for (int m = 0; m < 8; ++m) {
        const int rb = m0 + wrl + m * 16 + (lane >> 4) * 4;
        #pragma unroll
        for (int r = 0; r < 4; ++r) {
            const int row = rb + r;
            const int lab = label[row];
            const float ct = ctm[row];
            const float fv = fin[row];
            float* orow = out + (size_t)row * NCLS;
            #pragma unroll
            for (int n = 0; n < 4; ++n) {
                float c = acc[m][n][r] * kv[n];
                c = fminf(fmaxf(c, -1.f), 1.f);
                float v = (c > ct) ? c * (tnew + c) : c;
                v = (cols[n] == lab) ? fv : v;
                if (cols[n] < NCLS)
                    orow[cols[n]] = v * S_C;
            }
        }
    }
}

extern "C" void kernel_launch(void* const* d_in, const int* in_sizes, int n_in,
                              void* d_out, int out_size, void* d_ws, size_t ws_size,
                              hipStream_t stream) {
    const float* emb = (const float*)d_in[0];
    const float* Kg  = (const float*)d_in[1];
    const float* tin = (const float*)d_in[2];
    const int*   lab = (const int*)d_in[3];
    float* out = (float*)d_out;

    char* w = (char*)d_ws;
    u16*   Bn   = (u16*)w;                         // 391*131072*2 = 102,498,304
    u16*   Aw   = (u16*)(w + 102498304);           // 4*131072*2   =   1,048,576
    float* Af   = (float*)(w + 103546880);         // 1024*512*4   =   2,097,152
    float* kinv = (float*)(w + 105644032);         // CPAD*4       =     400,384
    float* tgt  = (float*)(w + 106044416);
    float* ctmv = (float*)(w + 106048512);
    float* finv = (float*)(w + 106052608);
    float* tnw  = (float*)(w + 106056704);

    norm_emb_k<<<NROWS, 64, 0, stream>>>(emb, Af, Aw);
    transpose_norm_k<<<NSTRIP, 256, 0, stream>>>(Kg, Bn, kinv);
    target_k<<<NROWS, 64, 0, stream>>>(Af, Bn, kinv, lab, tgt, ctmv, finv);
    tnew_k<<<1, 256, 0, stream>>>(tgt, tin, tnw);
    gemm_k<<<NWG, 512, 0, stream>>>(
        Aw, Bn, kinv, ctmv, finv, lab, tnw, out);
}